// Round 21
// baseline (162.585 us; speedup 1.0000x reference)
//
#include <hip/hip_runtime.h>
#include <hip/hip_fp16.h>

#define D_DIM 1024
#define NF 513            // rfft bins = D/2+1
#define NB 4              // batch
#define NS 2048           // sequence
#define NCH 256           // cumsum chunks (3-kernel scan: O(NCH) prefix)
#define CHS (NS / NCH)    // 8 steps per chunk
#define NQKV 3072         // 3*1024 packed freq rows (real bins 0,512 share a pair)
#define KOUT 1024         // packed spectral width, no padding
#define NTOK (NB * NS)    // 8192 tokens

typedef __attribute__((ext_vector_type(8))) short short8_t;   // 8 bf16 = 4 VGPRs
typedef __attribute__((ext_vector_type(4))) float f32x4;

__device__ inline unsigned short f2bf(float f) {
    unsigned u = __builtin_bit_cast(unsigned, f);
    u += 0x7FFFu + ((u >> 16) & 1u);   // round-to-nearest-even
    return (unsigned short)(u >> 16);
}
__device__ inline float bf2f(unsigned short h) {
    unsigned u = ((unsigned)h) << 16;
    return __builtin_bit_cast(float, u);
}
__device__ inline unsigned pkc(float re, float im) {   // packed bf16 pair
    return (unsigned)f2bf(re) | ((unsigned)f2bf(im) << 16);
}
__device__ inline float2 uph(unsigned u) {             // unpack fp16 pair
    unsigned short lo = (unsigned short)(u & 0xFFFFu), hi = (unsigned short)(u >> 16);
    return make_float2(__half2float(__builtin_bit_cast(__half, lo)),
                       __half2float(__builtin_bit_cast(__half, hi)));
}

// ---------------------------------------------------------------------------
// prep: blocks 0..2047 convert x -> bf16 (grid-stride); blocks 2048..2815 do
// the 64x64 LDS-tiled fp32 transpose of Wq/Wk/Wv -> WT[w][d][e].
// Independent outputs (xb vs WT); merged to save a dispatch + overlap BW/LDS.
// ---------------------------------------------------------------------------
__global__ __launch_bounds__(256) void prep(const float* __restrict__ x,
                                            const float* __restrict__ Wq,
                                            const float* __restrict__ Wk,
                                            const float* __restrict__ Wv,
                                            unsigned short* __restrict__ xb,
                                            float* __restrict__ WT) {
    const int bid = blockIdx.x;
    if (bid < 2048) {
        const int n4 = NTOK * D_DIM / 4;
        int i = bid * 256 + threadIdx.x;
        for (; i < n4; i += 2048 * 256) {
            float4 v = reinterpret_cast<const float4*>(x)[i];
            ushort4 o;
            o.x = f2bf(v.x); o.y = f2bf(v.y); o.z = f2bf(v.z); o.w = f2bf(v.w);
            reinterpret_cast<ushort4*>(xb)[i] = o;
        }
    } else {
        __shared__ float tile[64][65];
        const int t = bid - 2048;          // 0..767
        const int w = t >> 8;              // 0..2
        const int ti = t & 255;            // 16x16 tile grid
        const float* W = (w == 0) ? Wq : (w == 1) ? Wk : Wv;
        float* T = WT + (size_t)w * 1024 * 1024;
        const int bx = (ti & 15) * 64;
        const int by = (ti >> 4) * 64;
        const int tc = threadIdx.x & 63;
        const int tr = threadIdx.x >> 6;
        for (int r = tr; r < 64; r += 4)
            tile[r][tc] = W[(size_t)(by + r) * 1024 + bx + tc];
        __syncthreads();
        for (int r = tr; r < 64; r += 4)
            T[(size_t)(bx + r) * 1024 + by + tc] = tile[tc][r];
    }
}

__device__ inline void gload_lds16(const void* g, void* l) {
    __builtin_amdgcn_global_load_lds(
        (const __attribute__((address_space(1))) void*)g,
        (__attribute__((address_space(3))) void*)l,
        16, 0, 0);
}

// ---------------------------------------------------------------------------
// Proven 2-phase 128x128 BK=64 GEMM (R9/R13): 4 waves of 64x64, 2-buffer LDS
// (64 KB), counted vmcnt(8)/0, raw barriers, bank swizzle both-sides.
// F16OUT selects fp16 vs bf16 epilogue for 2-byte outputs.
// ---------------------------------------------------------------------------
template <typename OutT, bool F16OUT>
__global__ __launch_bounds__(256) void gemm_bf16_bk64(const unsigned short* __restrict__ A,
                                                      const unsigned short* __restrict__ B,
                                                      OutT* __restrict__ C,
                                                      int M, int N, int K) {
    __shared__ __attribute__((aligned(16))) unsigned short ldsA[2 * 128 * 64];
    __shared__ __attribute__((aligned(16))) unsigned short ldsB[2 * 128 * 64];
    const int tid  = threadIdx.x;
    const int wave = tid >> 6;
    const int lane = tid & 63;
    const int l15  = lane & 15;
    const int q4   = (lane >> 4) & 3;
    const int h7   = l15 & 7;
    const int p0   = ((q4)     ^ h7) << 3;
    const int p1   = ((4 + q4) ^ h7) << 3;
    const int wm   = (wave >> 1) * 64;
    const int wn   = (wave & 1) * 64;
    const int bm   = blockIdx.x * 128;
    const int bn   = blockIdx.y * 128;
    const int NT   = K >> 6;

    const unsigned short* Asrc = A + (size_t)(bm + (tid >> 3)) * K + (((tid & 7) ^ ((tid >> 3) & 7)) << 3);
    const unsigned short* Bsrc = B + (size_t)(bn + (tid >> 3)) * K + (((tid & 7) ^ ((tid >> 3) & 7)) << 3);
    const size_t cstep = (size_t)32 * K;

    f32x4 acc[4][4];
#pragma unroll
    for (int i = 0; i < 4; ++i)
#pragma unroll
        for (int j = 0; j < 4; ++j)
            acc[i][j] = (f32x4){0.f, 0.f, 0.f, 0.f};

    auto STAGE = [&](int t, int b) {
        const int k0 = t << 6;
        unsigned short* la = &ldsA[b * 8192 + tid * 8];
        unsigned short* lb = &ldsB[b * 8192 + tid * 8];
        gload_lds16(Asrc + k0,             la);
        gload_lds16(Asrc + cstep + k0,     la + 2048);
        gload_lds16(Asrc + 2 * cstep + k0, la + 4096);
        gload_lds16(Asrc + 3 * cstep + k0, la + 6144);
        gload_lds16(Bsrc + k0,             lb);
        gload_lds16(Bsrc + cstep + k0,     lb + 2048);
        gload_lds16(Bsrc + 2 * cstep + k0, lb + 4096);
        gload_lds16(Bsrc + 3 * cstep + k0, lb + 6144);
    };

    STAGE(0, 0);

    for (int j = 0; j < NT; ++j) {
        const int buf = j & 1;
        if (j + 1 < NT) {
            STAGE(j + 1, buf ^ 1);
            asm volatile("s_waitcnt vmcnt(8)" ::: "memory");
        } else {
            asm volatile("s_waitcnt vmcnt(0)" ::: "memory");
        }
        __builtin_amdgcn_s_barrier();
        asm volatile("" ::: "memory");

        const unsigned short* la = &ldsA[buf * 8192];
        const unsigned short* lb = &ldsB[buf * 8192];
        {
            short8_t af[4], bfv[4];
#pragma unroll
            for (int mi = 0; mi < 4; ++mi)
                af[mi] = *reinterpret_cast<const short8_t*>(&la[(wm + mi * 16 + l15) * 64 + p0]);
#pragma unroll
            for (int ni = 0; ni < 4; ++ni)
                bfv[ni] = *reinterpret_cast<const short8_t*>(&lb[(wn + ni * 16 + l15) * 64 + p0]);
            __builtin_amdgcn_s_setprio(1);
#pragma unroll
            for (int mi = 0; mi < 4; ++mi)
#pragma unroll
                for (int ni = 0; ni < 4; ++ni)
                    acc[mi][ni] = __builtin_amdgcn_mfma_f32_16x16x32_bf16(af[mi], bfv[ni], acc[mi][ni], 0, 0, 0);
            __builtin_amdgcn_s_setprio(0);
        }
        {
            short8_t af[4], bfv[4];
#pragma unroll
            for (int mi = 0; mi < 4; ++mi)
                af[mi] = *reinterpret_cast<const short8_t*>(&la[(wm + mi * 16 + l15) * 64 + p1]);
#pragma unroll
            for (int ni = 0; ni < 4; ++ni)
                bfv[ni] = *reinterpret_cast<const short8_t*>(&lb[(wn + ni * 16 + l15) * 64 + p1]);
            __builtin_amdgcn_s_setprio(1);
#pragma unroll
            for (int mi = 0; mi < 4; ++mi)
#pragma unroll
                for (int ni = 0; ni < 4; ++ni)
                    acc[mi][ni] = __builtin_amdgcn_mfma_f32_16x16x32_bf16(af[mi], bfv[ni], acc[mi][ni], 0, 0, 0);
            __builtin_amdgcn_s_setprio(0);
        }
        __builtin_amdgcn_s_barrier();
        asm volatile("" ::: "memory");
    }

#pragma unroll
    for (int mi = 0; mi < 4; ++mi) {
        int rbase = bm + wm + mi * 16 + (lane >> 4) * 4;
#pragma unroll
        for (int ni = 0; ni < 4; ++ni) {
            int col = bn + wn + ni * 16 + l15;
#pragma unroll
            for (int j = 0; j < 4; ++j) {
                float v = acc[mi][ni][j];
                if constexpr (sizeof(OutT) == 4)
                    C[(size_t)(rbase + j) * N + col] = v;
                else if constexpr (F16OUT)
                    C[(size_t)(rbase + j) * N + col] =
                        __builtin_bit_cast(unsigned short, __float2half(v));
                else
                    C[(size_t)(rbase + j) * N + col] = f2bf(v);
            }
        }
    }
}

// ---------------------------------------------------------------------------
// Radix-4 1024-pt complex FFT in LDS (proven): XOR bank swizzle, digit-rev.
// ---------------------------------------------------------------------------
__device__ inline int sw(int i) { return i ^ ((i >> 4) & 15); }

__device__ inline int dr4(int n) {
    return ((n & 3) << 8) | (((n >> 2) & 3) << 6) | (((n >> 4) & 3) << 4) |
           (((n >> 6) & 3) << 2) | ((n >> 8) & 3);
}

__device__ inline float2 cmul(float2 a, float2 b) {
    return make_float2(a.x * b.x - a.y * b.y, a.x * b.y + a.y * b.x);
}

__device__ inline void fft1024_r4(float2* X, const float2* tw, int t) {
#pragma unroll
    for (int s = 0; s < 5; ++s) {
        const int L = 1 << (2 * s);
        const int r = t & (L - 1);
        const int base = ((t >> (2 * s)) << (2 * s + 2)) + r;
        float2 A  = X[sw(base)];
        float2 Bv = X[sw(base + L)];
        float2 Cv = X[sw(base + 2 * L)];
        float2 Dv = X[sw(base + 3 * L)];
        if (s != 0) {
            const int step = 1024 >> (2 * s + 2);
            Bv = cmul(Bv, tw[sw(r * step)]);
            Cv = cmul(Cv, tw[sw(2 * r * step)]);
            Dv = cmul(Dv, tw[sw(3 * r * step)]);
        }
        float2 e0 = make_float2(A.x + Cv.x, A.y + Cv.y);
        float2 e1 = make_float2(A.x - Cv.x, A.y - Cv.y);
        float2 o0 = make_float2(Bv.x + Dv.x, Bv.y + Dv.y);
        float2 o1 = make_float2(Bv.x - Dv.x, Bv.y - Dv.y);
        X[sw(base)]         = make_float2(e0.x + o0.x, e0.y + o0.y);
        X[sw(base + L)]     = make_float2(e1.x + o1.y, e1.y - o1.x);
        X[sw(base + 2 * L)] = make_float2(e0.x - o0.x, e0.y - o0.y);
        X[sw(base + 3 * L)] = make_float2(e1.x - o1.y, e1.y + o1.x);
        __syncthreads();
    }
}

__device__ inline void twiddle_local(float2* twL, int tid) {
    for (int k = tid; k < 768; k += 256) {
        float ang = -6.283185307179586f * (float)k / 1024.0f;
        float s, c;
        sincosf(ang, &s, &c);
        twL[sw(k)] = make_float2(c, s);
    }
}

// ---------------------------------------------------------------------------
// Fused weight-FFT: blockIdx.y 0..2 -> QKV path (reads WT rows, packed rows
// of WF); blockIdx.y 3 -> Wo/Parseval path (reads Wo rows, packed cols of Wt).
// ---------------------------------------------------------------------------
__global__ __launch_bounds__(256) void wf_all(const float* __restrict__ WT,
                                              const float* __restrict__ Wo,
                                              unsigned short* __restrict__ WF,
                                              unsigned short* __restrict__ Wt) {
    __shared__ __attribute__((aligned(16))) float2 X[1024];
    __shared__ __attribute__((aligned(16))) float2 twL[768];
    const int tid = threadIdx.x;
    const int y = blockIdx.y;
    const int i0 = blockIdx.x * 2;
    twiddle_local(twL, tid);
    const float* r0 = (y < 3) ? (WT + (size_t)y * 1048576 + (size_t)i0 * 1024)
                              : (Wo + (size_t)i0 * 1024);
    const float* r1 = r0 + 1024;
    for (int n = tid; n < 1024; n += 256)
        X[sw(dr4(n))] = make_float2(r0[n], r1[n]);
    __syncthreads();
    fft1024_r4(X, twL, tid);
    if (y < 3) {
        const int rbase = y * 1024;
        for (int f = tid; f < NF; f += 256) {
            float2 Zj = X[sw(f)];
            float2 Zm = X[sw((1024 - f) & 1023)];
            float re0 = 0.5f * (Zj.x + Zm.x), im0 = 0.5f * (Zj.y - Zm.y);
            float re1 = 0.5f * (Zj.y + Zm.y), im1 = 0.5f * (Zm.x - Zj.x);
            if (f == 0) {
                WF[(size_t)(rbase + 0) * 1024 + i0]     = f2bf(re0);
                WF[(size_t)(rbase + 0) * 1024 + i0 + 1] = f2bf(re1);
            } else if (f == 512) {
                WF[(size_t)(rbase + 1) * 1024 + i0]     = f2bf(re0);
                WF[(size_t)(rbase + 1) * 1024 + i0 + 1] = f2bf(re1);
            } else {
                WF[(size_t)(rbase + 2 * f)     * 1024 + i0]     = f2bf(re0);
                WF[(size_t)(rbase + 2 * f + 1) * 1024 + i0]     = f2bf(im0);
                WF[(size_t)(rbase + 2 * f)     * 1024 + i0 + 1] = f2bf(re1);
                WF[(size_t)(rbase + 2 * f + 1) * 1024 + i0 + 1] = f2bf(im1);
            }
        }
    } else {
        unsigned short* o0 = Wt + (size_t)i0 * KOUT;
        unsigned short* o1 = o0 + KOUT;
        const float inv = 1.0f / 1024.0f;
        for (int f = tid; f < NF; f += 256) {
            float2 Zj = X[sw(f)];
            float2 Zm = X[sw((1024 - f) & 1023)];
            float re0 = 0.5f * (Zj.x + Zm.x), im0 = 0.5f * (Zj.y - Zm.y);
            float re1 = 0.5f * (Zj.y + Zm.y), im1 = 0.5f * (Zm.x - Zj.x);
            if (f == 0) {
                o0[0] = f2bf(re0 * inv);
                o1[0] = f2bf(re1 * inv);
            } else if (f == 512) {
                o0[1] = f2bf(re0 * inv);
                o1[1] = f2bf(re1 * inv);
            } else {
                float c = 2.0f * inv;
                o0[2 * f]     = f2bf(re0 * c);
                o0[2 * f + 1] = f2bf(im0 * c);
                o1[2 * f]     = f2bf(re1 * c);
                o1[2 * f + 1] = f2bf(im1 * c);
            }
        }
    }
}

// ---------------------------------------------------------------------------
// 3-kernel chunked scan, NCH=256 (CHS=8): chunk_sum (2048 blocks) ->
// prefix (O(NCH) per thread, coalesced, L2-hot) -> apply (2048 blocks).
// F_all rows: [8192][1536] packed fp16 u32 (Fq | Fk | Fv, 512 u32 each).
// u32 idx 0 of each section = (Re bin0, Re bin512); idx f=1..511 = (Re,Im).
// ---------------------------------------------------------------------------
__global__ __launch_bounds__(256) void hrr_chunk_sum(const unsigned* __restrict__ F,
                                                     float2* __restrict__ part) {
    int f = blockIdx.x * 256 + threadIdx.x;   // 0..511
    int ch = blockIdx.y, b = blockIdx.z;
    size_t base = ((size_t)b * NS + (size_t)ch * CHS) * 1536;
    float2* pp = part + (size_t)(b * NCH + ch) * NF;
    if (f == 0) {
        float s0 = 0.f, s512 = 0.f;
        for (int i = 0; i < CHS; ++i) {
            size_t row = base + (size_t)i * 1536;
            float2 k = uph(F[row + 512]);
            float2 v = uph(F[row + 1024]);
            s0   += k.x * v.x;
            s512 += k.y * v.y;
        }
        pp[0]   = make_float2(s0, 0.f);
        pp[512] = make_float2(s512, 0.f);
    } else {
        float sx = 0.f, sy = 0.f;
        for (int i = 0; i < CHS; ++i) {
            size_t row = base + (size_t)i * 1536;
            float2 k = uph(F[row + 512 + f]);
            float2 v = uph(F[row + 1024 + f]);
            sx += k.x * v.x - k.y * v.y;
            sy += k.x * v.y + k.y * v.x;
        }
        pp[f] = make_float2(sx, sy);
    }
}

// exclusive prefix over chunks, in place.  Thread per (b,f); loads are
// address-independent (pipelined), only the fp32 add chain is serial.
__global__ __launch_bounds__(256) void hrr_prefix(float2* __restrict__ part) {
    int f = blockIdx.x * 256 + threadIdx.x;
    int b = blockIdx.y;
    if (f >= NF) return;
    float rx = 0.f, ry = 0.f;
    for (int ch = 0; ch < NCH; ++ch) {
        size_t idx = ((size_t)b * NCH + ch) * NF + f;
        float2 t = part[idx];
        part[idx] = make_float2(rx, ry);
        rx += t.x; ry += t.y;
    }
}

__global__ __launch_bounds__(256) void hrr_scan_apply(const unsigned* __restrict__ F,
                                                      const float2* __restrict__ part,
                                                      unsigned* __restrict__ U) {
    int f = blockIdx.x * 256 + threadIdx.x;   // 0..511
    int ch = blockIdx.y, b = blockIdx.z;
    size_t base  = ((size_t)b * NS + (size_t)ch * CHS) * 1536;
    size_t ubase = ((size_t)b * NS + (size_t)ch * CHS) * 512;
    const float2* pp = part + (size_t)(b * NCH + ch) * NF;
    if (f == 0) {
        float r0 = pp[0].x, r512 = pp[512].x;
        for (int i = 0; i < CHS; ++i) {
            size_t row = base + (size_t)i * 1536;
            float2 k = uph(F[row + 512]);
            float2 v = uph(F[row + 1024]);
            float2 q = uph(F[row]);
            r0   += k.x * v.x;
            r512 += k.y * v.y;
            U[ubase + (size_t)i * 512] = pkc(r0 * q.x, r512 * q.y);
        }
    } else {
        float2 p = pp[f];
        float rx = p.x, ry = p.y;
        for (int i = 0; i < CHS; ++i) {
            size_t row = base + (size_t)i * 1536;
            float2 k = uph(F[row + 512 + f]);
            float2 v = uph(F[row + 1024 + f]);
            rx += k.x * v.x - k.y * v.y;
            ry += k.x * v.y + k.y * v.x;
            float2 q = uph(F[row + f]);
            U[ubase + (size_t)i * 512 + f] = pkc(rx * q.x + ry * q.y,
                                                 ry * q.x - rx * q.y);
        }
    }
}

// ---------------------------------------------------------------------------
extern "C" void kernel_launch(void* const* d_in, const int* in_sizes, int n_in,
                              void* d_out, int out_size, void* d_ws, size_t ws_size,
                              hipStream_t stream) {
    const float* x  = (const float*)d_in[0];
    const float* Wq = (const float*)d_in[1];
    const float* Wk = (const float*)d_in[2];
    const float* Wv = (const float*)d_in[3];
    const float* Wo = (const float*)d_in[4];
    float* out = (float*)d_out;

    char* ws = (char*)d_ws;
    unsigned short* F_all = (unsigned short*)(ws + 0);         // 50,331,648
    unsigned short* U     = (unsigned short*)(ws + 50331648);  // 16,777,216
    float2*         part  = (float2*)        (ws + 67108864);  // 4*256*513*8 = 4,202,496
    unsigned short* WF    = (unsigned short*)(ws + 71311360);  // 6,291,456
    unsigned short* Wt    = (unsigned short*)(ws + 77602816);  // 2,097,152
    unsigned short* xb    = (unsigned short*)(ws + 79699968);  // 16,777,216 (end ~96.5 MB)
    float* WT = (float*)U;   // transpose scratch aliases U (stream-ordered)

    // convert_x + transpose_w in one dispatch (independent outputs)
    prep<<<2048 + 768, 256, 0, stream>>>(x, Wq, Wk, Wv, xb, WT);
    wf_all<<<dim3(512, 4), 256, 0, stream>>>(WT, Wo, WF, Wt);

    // Fused projection+FFT: F_all[t] = (Fq | Fk | Fv) packed fp16
    dim3 gq(NTOK / 128, NQKV / 128);
    gemm_bf16_bk64<unsigned short, true><<<gq, 256, 0, stream>>>(xb, WF, F_all, NTOK, NQKV, D_DIM);

    dim3 gs(2, NCH, NB);
    hrr_chunk_sum<<<gs, 256, 0, stream>>>((const unsigned*)F_all, part);
    hrr_prefix<<<dim3(3, NB), 256, 0, stream>>>(part);
    hrr_scan_apply<<<gs, 256, 0, stream>>>((const unsigned*)F_all, part, (unsigned*)U);

    // Fused irfft+output projection (Parseval): out = U @ Wt^T
    dim3 go(NTOK / 128, D_DIM / 128);
    gemm_bf16_bk64<float, false><<<go, 256, 0, stream>>>(U, Wt, out, NTOK, D_DIM, KOUT);
}

// Round 22
// 155.960 us; speedup vs baseline: 1.0425x; 1.0425x over previous
//
#include <hip/hip_runtime.h>
#include <hip/hip_fp16.h>

#define D_DIM 1024
#define NF 513            // rfft bins = D/2+1
#define NB 4              // batch
#define NS 2048           // sequence
#define NCH 128           // cumsum chunks (3-kernel scan: O(NCH) prefix)
#define CHS (NS / NCH)    // 16 steps per chunk
#define NQKV 3072         // 3*1024 packed freq rows (real bins 0,512 share a pair)
#define KOUT 1024         // packed spectral width, no padding
#define NTOK (NB * NS)    // 8192 tokens

typedef __attribute__((ext_vector_type(8))) short short8_t;   // 8 bf16 = 4 VGPRs
typedef __attribute__((ext_vector_type(4))) float f32x4;

__device__ inline unsigned short f2bf(float f) {
    unsigned u = __builtin_bit_cast(unsigned, f);
    u += 0x7FFFu + ((u >> 16) & 1u);   // round-to-nearest-even
    return (unsigned short)(u >> 16);
}
__device__ inline float bf2f(unsigned short h) {
    unsigned u = ((unsigned)h) << 16;
    return __builtin_bit_cast(float, u);
}
__device__ inline unsigned pkc(float re, float im) {   // packed bf16 pair
    return (unsigned)f2bf(re) | ((unsigned)f2bf(im) << 16);
}
__device__ inline float2 uph(unsigned u) {             // unpack fp16 pair
    unsigned short lo = (unsigned short)(u & 0xFFFFu), hi = (unsigned short)(u >> 16);
    return make_float2(__half2float(__builtin_bit_cast(__half, lo)),
                       __half2float(__builtin_bit_cast(__half, hi)));
}

__global__ __launch_bounds__(256) void convert_x(const float* __restrict__ src,
                                                 unsigned short* __restrict__ dst,
                                                 int n4) {
    int i = blockIdx.x * 256 + threadIdx.x;
    int stride = gridDim.x * 256;
    for (; i < n4; i += stride) {
        float4 v = reinterpret_cast<const float4*>(src)[i];
        ushort4 o;
        o.x = f2bf(v.x); o.y = f2bf(v.y); o.z = f2bf(v.z); o.w = f2bf(v.w);
        reinterpret_cast<ushort4*>(dst)[i] = o;
    }
}

// ---------------------------------------------------------------------------
// 64x64 LDS-tiled fp32 transpose of Wq/Wk/Wv -> WT[w][d][e].
// ---------------------------------------------------------------------------
__global__ __launch_bounds__(256) void transpose_w(const float* __restrict__ Wq,
                                                   const float* __restrict__ Wk,
                                                   const float* __restrict__ Wv,
                                                   float* __restrict__ WT) {
    __shared__ float tile[64][65];
    const int w = blockIdx.z;
    const float* W = (w == 0) ? Wq : (w == 1) ? Wk : Wv;
    float* T = WT + (size_t)w * 1024 * 1024;
    const int bx = blockIdx.x * 64;
    const int by = blockIdx.y * 64;
    const int tc = threadIdx.x & 63;
    const int tr = threadIdx.x >> 6;
    for (int r = tr; r < 64; r += 4)
        tile[r][tc] = W[(size_t)(by + r) * 1024 + bx + tc];
    __syncthreads();
    for (int r = tr; r < 64; r += 4)
        T[(size_t)(bx + r) * 1024 + by + tc] = tile[tc][r];
}

__device__ inline void gload_lds16(const void* g, void* l) {
    __builtin_amdgcn_global_load_lds(
        (const __attribute__((address_space(1))) void*)g,
        (__attribute__((address_space(3))) void*)l,
        16, 0, 0);
}

// ---------------------------------------------------------------------------
// Proven 2-phase 128x128 BK=64 GEMM (R9/R13): 4 waves of 64x64, 2-buffer LDS
// (64 KB), counted vmcnt(8)/0, raw barriers, bank swizzle both-sides.
// F16OUT selects fp16 vs bf16 epilogue for 2-byte outputs.
// ---------------------------------------------------------------------------
template <typename OutT, bool F16OUT>
__global__ __launch_bounds__(256) void gemm_bf16_bk64(const unsigned short* __restrict__ A,
                                                      const unsigned short* __restrict__ B,
                                                      OutT* __restrict__ C,
                                                      int M, int N, int K) {
    __shared__ __attribute__((aligned(16))) unsigned short ldsA[2 * 128 * 64];
    __shared__ __attribute__((aligned(16))) unsigned short ldsB[2 * 128 * 64];
    const int tid  = threadIdx.x;
    const int wave = tid >> 6;
    const int lane = tid & 63;
    const int l15  = lane & 15;
    const int q4   = (lane >> 4) & 3;
    const int h7   = l15 & 7;
    const int p0   = ((q4)     ^ h7) << 3;
    const int p1   = ((4 + q4) ^ h7) << 3;
    const int wm   = (wave >> 1) * 64;
    const int wn   = (wave & 1) * 64;
    const int bm   = blockIdx.x * 128;
    const int bn   = blockIdx.y * 128;
    const int NT   = K >> 6;

    const unsigned short* Asrc = A + (size_t)(bm + (tid >> 3)) * K + (((tid & 7) ^ ((tid >> 3) & 7)) << 3);
    const unsigned short* Bsrc = B + (size_t)(bn + (tid >> 3)) * K + (((tid & 7) ^ ((tid >> 3) & 7)) << 3);
    const size_t cstep = (size_t)32 * K;

    f32x4 acc[4][4];
#pragma unroll
    for (int i = 0; i < 4; ++i)
#pragma unroll
        for (int j = 0; j < 4; ++j)
            acc[i][j] = (f32x4){0.f, 0.f, 0.f, 0.f};

    auto STAGE = [&](int t, int b) {
        const int k0 = t << 6;
        unsigned short* la = &ldsA[b * 8192 + tid * 8];
        unsigned short* lb = &ldsB[b * 8192 + tid * 8];
        gload_lds16(Asrc + k0,             la);
        gload_lds16(Asrc + cstep + k0,     la + 2048);
        gload_lds16(Asrc + 2 * cstep + k0, la + 4096);
        gload_lds16(Asrc + 3 * cstep + k0, la + 6144);
        gload_lds16(Bsrc + k0,             lb);
        gload_lds16(Bsrc + cstep + k0,     lb + 2048);
        gload_lds16(Bsrc + 2 * cstep + k0, lb + 4096);
        gload_lds16(Bsrc + 3 * cstep + k0, lb + 6144);
    };

    STAGE(0, 0);

    for (int j = 0; j < NT; ++j) {
        const int buf = j & 1;
        if (j + 1 < NT) {
            STAGE(j + 1, buf ^ 1);
            asm volatile("s_waitcnt vmcnt(8)" ::: "memory");
        } else {
            asm volatile("s_waitcnt vmcnt(0)" ::: "memory");
        }
        __builtin_amdgcn_s_barrier();
        asm volatile("" ::: "memory");

        const unsigned short* la = &ldsA[buf * 8192];
        const unsigned short* lb = &ldsB[buf * 8192];
        {
            short8_t af[4], bfv[4];
#pragma unroll
            for (int mi = 0; mi < 4; ++mi)
                af[mi] = *reinterpret_cast<const short8_t*>(&la[(wm + mi * 16 + l15) * 64 + p0]);
#pragma unroll
            for (int ni = 0; ni < 4; ++ni)
                bfv[ni] = *reinterpret_cast<const short8_t*>(&lb[(wn + ni * 16 + l15) * 64 + p0]);
            __builtin_amdgcn_s_setprio(1);
#pragma unroll
            for (int mi = 0; mi < 4; ++mi)
#pragma unroll
                for (int ni = 0; ni < 4; ++ni)
                    acc[mi][ni] = __builtin_amdgcn_mfma_f32_16x16x32_bf16(af[mi], bfv[ni], acc[mi][ni], 0, 0, 0);
            __builtin_amdgcn_s_setprio(0);
        }
        {
            short8_t af[4], bfv[4];
#pragma unroll
            for (int mi = 0; mi < 4; ++mi)
                af[mi] = *reinterpret_cast<const short8_t*>(&la[(wm + mi * 16 + l15) * 64 + p1]);
#pragma unroll
            for (int ni = 0; ni < 4; ++ni)
                bfv[ni] = *reinterpret_cast<const short8_t*>(&lb[(wn + ni * 16 + l15) * 64 + p1]);
            __builtin_amdgcn_s_setprio(1);
#pragma unroll
            for (int mi = 0; mi < 4; ++mi)
#pragma unroll
                for (int ni = 0; ni < 4; ++ni)
                    acc[mi][ni] = __builtin_amdgcn_mfma_f32_16x16x32_bf16(af[mi], bfv[ni], acc[mi][ni], 0, 0, 0);
            __builtin_amdgcn_s_setprio(0);
        }
        __builtin_amdgcn_s_barrier();
        asm volatile("" ::: "memory");
    }

#pragma unroll
    for (int mi = 0; mi < 4; ++mi) {
        int rbase = bm + wm + mi * 16 + (lane >> 4) * 4;
#pragma unroll
        for (int ni = 0; ni < 4; ++ni) {
            int col = bn + wn + ni * 16 + l15;
#pragma unroll
            for (int j = 0; j < 4; ++j) {
                float v = acc[mi][ni][j];
                if constexpr (sizeof(OutT) == 4)
                    C[(size_t)(rbase + j) * N + col] = v;
                else if constexpr (F16OUT)
                    C[(size_t)(rbase + j) * N + col] =
                        __builtin_bit_cast(unsigned short, __float2half(v));
                else
                    C[(size_t)(rbase + j) * N + col] = f2bf(v);
            }
        }
    }
}

// ---------------------------------------------------------------------------
// Radix-4 1024-pt complex FFT in LDS (proven): XOR bank swizzle, digit-rev.
// ---------------------------------------------------------------------------
__device__ inline int sw(int i) { return i ^ ((i >> 4) & 15); }

__device__ inline int dr4(int n) {
    return ((n & 3) << 8) | (((n >> 2) & 3) << 6) | (((n >> 4) & 3) << 4) |
           (((n >> 6) & 3) << 2) | ((n >> 8) & 3);
}

__device__ inline float2 cmul(float2 a, float2 b) {
    return make_float2(a.x * b.x - a.y * b.y, a.x * b.y + a.y * b.x);
}

__device__ inline void fft1024_r4(float2* X, const float2* tw, int t) {
#pragma unroll
    for (int s = 0; s < 5; ++s) {
        const int L = 1 << (2 * s);
        const int r = t & (L - 1);
        const int base = ((t >> (2 * s)) << (2 * s + 2)) + r;
        float2 A  = X[sw(base)];
        float2 Bv = X[sw(base + L)];
        float2 Cv = X[sw(base + 2 * L)];
        float2 Dv = X[sw(base + 3 * L)];
        if (s != 0) {
            const int step = 1024 >> (2 * s + 2);
            Bv = cmul(Bv, tw[sw(r * step)]);
            Cv = cmul(Cv, tw[sw(2 * r * step)]);
            Dv = cmul(Dv, tw[sw(3 * r * step)]);
        }
        float2 e0 = make_float2(A.x + Cv.x, A.y + Cv.y);
        float2 e1 = make_float2(A.x - Cv.x, A.y - Cv.y);
        float2 o0 = make_float2(Bv.x + Dv.x, Bv.y + Dv.y);
        float2 o1 = make_float2(Bv.x - Dv.x, Bv.y - Dv.y);
        X[sw(base)]         = make_float2(e0.x + o0.x, e0.y + o0.y);
        X[sw(base + L)]     = make_float2(e1.x + o1.y, e1.y - o1.x);
        X[sw(base + 2 * L)] = make_float2(e0.x - o0.x, e0.y - o0.y);
        X[sw(base + 3 * L)] = make_float2(e1.x - o1.y, e1.y + o1.x);
        __syncthreads();
    }
}

__device__ inline void twiddle_local(float2* twL, int tid) {
    for (int k = tid; k < 768; k += 256) {
        float ang = -6.283185307179586f * (float)k / 1024.0f;
        float s, c;
        sincosf(ang, &s, &c);
        twL[sw(k)] = make_float2(c, s);
    }
}

// ---------------------------------------------------------------------------
// Fused weight-FFT: blockIdx.y 0..2 -> QKV path (reads WT rows, packed rows
// of WF); blockIdx.y 3 -> Wo/Parseval path (reads Wo rows, packed cols of Wt).
// ---------------------------------------------------------------------------
__global__ __launch_bounds__(256) void wf_all(const float* __restrict__ WT,
                                              const float* __restrict__ Wo,
                                              unsigned short* __restrict__ WF,
                                              unsigned short* __restrict__ Wt) {
    __shared__ __attribute__((aligned(16))) float2 X[1024];
    __shared__ __attribute__((aligned(16))) float2 twL[768];
    const int tid = threadIdx.x;
    const int y = blockIdx.y;
    const int i0 = blockIdx.x * 2;
    twiddle_local(twL, tid);
    const float* r0 = (y < 3) ? (WT + (size_t)y * 1048576 + (size_t)i0 * 1024)
                              : (Wo + (size_t)i0 * 1024);
    const float* r1 = r0 + 1024;
    for (int n = tid; n < 1024; n += 256)
        X[sw(dr4(n))] = make_float2(r0[n], r1[n]);
    __syncthreads();
    fft1024_r4(X, twL, tid);
    if (y < 3) {
        const int rbase = y * 1024;
        for (int f = tid; f < NF; f += 256) {
            float2 Zj = X[sw(f)];
            float2 Zm = X[sw((1024 - f) & 1023)];
            float re0 = 0.5f * (Zj.x + Zm.x), im0 = 0.5f * (Zj.y - Zm.y);
            float re1 = 0.5f * (Zj.y + Zm.y), im1 = 0.5f * (Zm.x - Zj.x);
            if (f == 0) {
                WF[(size_t)(rbase + 0) * 1024 + i0]     = f2bf(re0);
                WF[(size_t)(rbase + 0) * 1024 + i0 + 1] = f2bf(re1);
            } else if (f == 512) {
                WF[(size_t)(rbase + 1) * 1024 + i0]     = f2bf(re0);
                WF[(size_t)(rbase + 1) * 1024 + i0 + 1] = f2bf(re1);
            } else {
                WF[(size_t)(rbase + 2 * f)     * 1024 + i0]     = f2bf(re0);
                WF[(size_t)(rbase + 2 * f + 1) * 1024 + i0]     = f2bf(im0);
                WF[(size_t)(rbase + 2 * f)     * 1024 + i0 + 1] = f2bf(re1);
                WF[(size_t)(rbase + 2 * f + 1) * 1024 + i0 + 1] = f2bf(im1);
            }
        }
    } else {
        unsigned short* o0 = Wt + (size_t)i0 * KOUT;
        unsigned short* o1 = o0 + KOUT;
        const float inv = 1.0f / 1024.0f;
        for (int f = tid; f < NF; f += 256) {
            float2 Zj = X[sw(f)];
            float2 Zm = X[sw((1024 - f) & 1023)];
            float re0 = 0.5f * (Zj.x + Zm.x), im0 = 0.5f * (Zj.y - Zm.y);
            float re1 = 0.5f * (Zj.y + Zm.y), im1 = 0.5f * (Zm.x - Zj.x);
            if (f == 0) {
                o0[0] = f2bf(re0 * inv);
                o1[0] = f2bf(re1 * inv);
            } else if (f == 512) {
                o0[1] = f2bf(re0 * inv);
                o1[1] = f2bf(re1 * inv);
            } else {
                float c = 2.0f * inv;
                o0[2 * f]     = f2bf(re0 * c);
                o0[2 * f + 1] = f2bf(im0 * c);
                o1[2 * f]     = f2bf(re1 * c);
                o1[2 * f + 1] = f2bf(im1 * c);
            }
        }
    }
}

// ---------------------------------------------------------------------------
// 3-kernel chunked scan, NCH=128 (CHS=16): chunk_sum (1024 blocks) ->
// prefix (O(NCH) per thread, coalesced, L2-hot) -> apply (1024 blocks).
// F_all rows: [8192][1536] packed fp16 u32 (Fq | Fk | Fv, 512 u32 each).
// u32 idx 0 of each section = (Re bin0, Re bin512); idx f=1..511 = (Re,Im).
// ---------------------------------------------------------------------------
__global__ __launch_bounds__(256) void hrr_chunk_sum(const unsigned* __restrict__ F,
                                                     float2* __restrict__ part) {
    int f = blockIdx.x * 256 + threadIdx.x;   // 0..511
    int ch = blockIdx.y, b = blockIdx.z;
    size_t base = ((size_t)b * NS + (size_t)ch * CHS) * 1536;
    float2* pp = part + (size_t)(b * NCH + ch) * NF;
    if (f == 0) {
        float s0 = 0.f, s512 = 0.f;
        for (int i = 0; i < CHS; ++i) {
            size_t row = base + (size_t)i * 1536;
            float2 k = uph(F[row + 512]);
            float2 v = uph(F[row + 1024]);
            s0   += k.x * v.x;
            s512 += k.y * v.y;
        }
        pp[0]   = make_float2(s0, 0.f);
        pp[512] = make_float2(s512, 0.f);
    } else {
        float sx = 0.f, sy = 0.f;
        for (int i = 0; i < CHS; ++i) {
            size_t row = base + (size_t)i * 1536;
            float2 k = uph(F[row + 512 + f]);
            float2 v = uph(F[row + 1024 + f]);
            sx += k.x * v.x - k.y * v.y;
            sy += k.x * v.y + k.y * v.x;
        }
        pp[f] = make_float2(sx, sy);
    }
}

// exclusive prefix over chunks, in place.  Thread per (b,f); loads are
// address-independent (pipelined), only the fp32 add chain is serial.
__global__ __launch_bounds__(256) void hrr_prefix(float2* __restrict__ part) {
    int f = blockIdx.x * 256 + threadIdx.x;
    int b = blockIdx.y;
    if (f >= NF) return;
    float rx = 0.f, ry = 0.f;
    for (int ch = 0; ch < NCH; ++ch) {
        size_t idx = ((size_t)b * NCH + ch) * NF + f;
        float2 t = part[idx];
        part[idx] = make_float2(rx, ry);
        rx += t.x; ry += t.y;
    }
}

__global__ __launch_bounds__(256) void hrr_scan_apply(const unsigned* __restrict__ F,
                                                      const float2* __restrict__ part,
                                                      unsigned* __restrict__ U) {
    int f = blockIdx.x * 256 + threadIdx.x;   // 0..511
    int ch = blockIdx.y, b = blockIdx.z;
    size_t base  = ((size_t)b * NS + (size_t)ch * CHS) * 1536;
    size_t ubase = ((size_t)b * NS + (size_t)ch * CHS) * 512;
    const float2* pp = part + (size_t)(b * NCH + ch) * NF;
    if (f == 0) {
        float r0 = pp[0].x, r512 = pp[512].x;
        for (int i = 0; i < CHS; ++i) {
            size_t row = base + (size_t)i * 1536;
            float2 k = uph(F[row + 512]);
            float2 v = uph(F[row + 1024]);
            float2 q = uph(F[row]);
            r0   += k.x * v.x;
            r512 += k.y * v.y;
            U[ubase + (size_t)i * 512] = pkc(r0 * q.x, r512 * q.y);
        }
    } else {
        float2 p = pp[f];
        float rx = p.x, ry = p.y;
        for (int i = 0; i < CHS; ++i) {
            size_t row = base + (size_t)i * 1536;
            float2 k = uph(F[row + 512 + f]);
            float2 v = uph(F[row + 1024 + f]);
            rx += k.x * v.x - k.y * v.y;
            ry += k.x * v.y + k.y * v.x;
            float2 q = uph(F[row + f]);
            U[ubase + (size_t)i * 512 + f] = pkc(rx * q.x + ry * q.y,
                                                 ry * q.x - rx * q.y);
        }
    }
}

// ---------------------------------------------------------------------------
extern "C" void kernel_launch(void* const* d_in, const int* in_sizes, int n_in,
                              void* d_out, int out_size, void* d_ws, size_t ws_size,
                              hipStream_t stream) {
    const float* x  = (const float*)d_in[0];
    const float* Wq = (const float*)d_in[1];
    const float* Wk = (const float*)d_in[2];
    const float* Wv = (const float*)d_in[3];
    const float* Wo = (const float*)d_in[4];
    float* out = (float*)d_out;

    char* ws = (char*)d_ws;
    unsigned short* F_all = (unsigned short*)(ws + 0);         // 50,331,648
    unsigned short* U     = (unsigned short*)(ws + 50331648);  // 16,777,216
    float2*         part  = (float2*)        (ws + 67108864);  // 4*128*513*8 = 2,101,248
    unsigned short* WF    = (unsigned short*)(ws + 69210112);  // 6,291,456
    unsigned short* Wt    = (unsigned short*)(ws + 75501568);  // 2,097,152
    unsigned short* xb    = (unsigned short*)(ws + 77598720);  // 16,777,216 (end ~94.4 MB)
    float* WT = (float*)U;   // transpose scratch aliases U (stream-ordered)

    convert_x<<<2048, 256, 0, stream>>>(x, xb, NTOK * D_DIM / 4);

    transpose_w<<<dim3(16, 16, 3), 256, 0, stream>>>(Wq, Wk, Wv, WT);
    wf_all<<<dim3(512, 4), 256, 0, stream>>>(WT, Wo, WF, Wt);

    // Fused projection+FFT: F_all[t] = (Fq | Fk | Fv) packed fp16
    dim3 gq(NTOK / 128, NQKV / 128);
    gemm_bf16_bk64<unsigned short, true><<<gq, 256, 0, stream>>>(xb, WF, F_all, NTOK, NQKV, D_DIM);

    dim3 gs(2, NCH, NB);
    hrr_chunk_sum<<<gs, 256, 0, stream>>>((const unsigned*)F_all, part);
    hrr_prefix<<<dim3(3, NB), 256, 0, stream>>>(part);
    hrr_scan_apply<<<gs, 256, 0, stream>>>((const unsigned*)F_all, part, (unsigned*)U);

    // Fused irfft+output projection (Parseval): out = U @ Wt^T
    dim3 go(NTOK / 128, D_DIM / 128);
    gemm_bf16_bk64<float, false><<<go, 256, 0, stream>>>(U, Wt, out, NTOK, D_DIM, KOUT);
}